// Round 12
// baseline (198.121 us; speedup 1.0000x reference)
//
#include <hip/hip_runtime.h>

// ---- problem constants ----
constexpr int   kT    = 1002;
constexpr int   kD    = 16;
constexpr int   kE    = 32;
constexpr int   kH    = 64;
constexpr int   kLen  = kT - 2;     // 1000
constexpr int   kN    = 32 * kLen;  // 32000
constexpr float kSlope = 0.2f;
constexpr int   AS    = 68;         // act row stride (floats)
// per-d ws dwords: fwd bf16 3-level (w0 3*1024 @0, w1 3*2048 @3072, w2 3*2048 @9216),
// jac fp16 2-level (w1 @15360/17408, w2 @19456/21504)
constexpr int   kWsDwPerD   = 23552;
constexpr int   kWsEmbBase  = 16 * kWsDwPerD;       // 376832 dwords
constexpr int   kEmbRowDw   = 48;                    // 3 levels x 16 dwords
constexpr int   kWsEmbDw    = kN * kEmbRowDw;        // 1,536,000 dwords
constexpr int   kPrepW      = 16 * 9216;             // weight work items
constexpr int   kPrepE      = kN * 16;               // emb pair work items

typedef __attribute__((ext_vector_type(8))) short bf16x8;
typedef __attribute__((ext_vector_type(4))) float f32x4;
typedef __attribute__((ext_vector_type(2))) __fp16 fp16x2;     // cvt_pkrtz result type
typedef __attribute__((ext_vector_type(8))) _Float16 f16x8;    // MFMA f16 operand type

// ---------------- bf16 splits ----------------
// RNE pair-round (full accuracy — used in prep where it's free)
__device__ __forceinline__ unsigned rne2(float x0, float x1, float &h0, float &h1) {
    unsigned u0 = __float_as_uint(x0), u1 = __float_as_uint(x1);
    unsigned r0 = u0 + 0x7FFFu + ((u0 >> 16) & 1u);
    unsigned r1 = u1 + 0x7FFFu + ((u1 >> 16) & 1u);
    h0 = __uint_as_float(r0 & 0xFFFF0000u);
    h1 = __uint_as_float(r1 & 0xFFFF0000u);
    return __builtin_amdgcn_perm(r1, r0, 0x07060302u);  // [r0.hi16 | r1.hi16<<16]
}

// truncation pair-round (cheap — 3 ops): h = x with low 16 bits cleared (exact x-h)
__device__ __forceinline__ unsigned trunc2(float x0, float x1, float &h0, float &h1) {
    unsigned u0 = __float_as_uint(x0), u1 = __float_as_uint(x1);
    h0 = __uint_as_float(u0 & 0xFFFF0000u);
    h1 = __uint_as_float(u1 & 0xFFFF0000u);
    return __builtin_amdgcn_perm(u1, u0, 0x07060302u);
}

// full-RNE 3-way split (prep: weights + emb)
__device__ __forceinline__ void split3_2(float x0, float x1,
                                         unsigned &p1, unsigned &p2, unsigned &p3) {
    float h0, h1; p1 = rne2(x0, x1, h0, h1);
    float e0 = x0 - h0, e1 = x1 - h1;      // exact
    float m0, m1; p2 = rne2(e0, e1, m0, m1);
    float f0 = e0 - m0, f1 = e1 - m1;      // exact
    float t0, t1; p3 = rne2(f0, f1, t0, t1);
}

// trunc-trunc-RNE 3-way split (main-kernel act splits). Only the LAST level's
// rounding survives as error (e1,e2 exact), so this is ~2x all-RNE (2^-25 vs
// 2^-26 rel) at 15 vs 23 VALU ops/pair.
__device__ __forceinline__ void split3t_2(float x0, float x1,
                                          unsigned &p1, unsigned &p2, unsigned &p3) {
    float h0, h1; p1 = trunc2(x0, x1, h0, h1);
    float e0 = x0 - h0, e1 = x1 - h1;      // exact
    float m0, m1; p2 = trunc2(e0, e1, m0, m1);
    float f0 = e0 - m0, f1 = e1 - m1;      // exact
    float t0, t1; p3 = rne2(f0, f1, t0, t1);   // h outputs DCE'd
}

union FragU { unsigned u[4]; bf16x8 v; };

__device__ __forceinline__ void splitA3t(const float4 a0, const float4 a1,
                                         bf16x8 &A1, bf16x8 &A2, bf16x8 &A3) {
    FragU U1, U2, U3;
    split3t_2(a0.x, a0.y, U1.u[0], U2.u[0], U3.u[0]);
    split3t_2(a0.z, a0.w, U1.u[1], U2.u[1], U3.u[1]);
    split3t_2(a1.x, a1.y, U1.u[2], U2.u[2], U3.u[2]);
    split3t_2(a1.z, a1.w, U1.u[3], U2.u[3], U3.u[3]);
    A1 = U1.v; A2 = U2.v; A3 = U3.v;
}

// ---------------- fp16 splits (Jacobian path: values only, ~21-bit) ----------------
__device__ __forceinline__ void split2h(float x0, float x1, unsigned &p1, unsigned &p2) {
    fp16x2 h = __builtin_amdgcn_cvt_pkrtz(x0, x1);
    __builtin_memcpy(&p1, &h, 4);
    fp16x2 l = __builtin_amdgcn_cvt_pkrtz(x0 - (float)h[0], x1 - (float)h[1]);
    __builtin_memcpy(&p2, &l, 4);
}

union FragH { unsigned u[4]; f16x8 v; };

__device__ __forceinline__ void splitA2h(const float4 a0, const float4 a1,
                                         f16x8 &A1, f16x8 &A2) {
    FragH U1, U2;
    split2h(a0.x, a0.y, U1.u[0], U2.u[0]);
    split2h(a0.z, a0.w, U1.u[1], U2.u[1]);
    split2h(a1.x, a1.y, U1.u[2], U2.u[2]);
    split2h(a1.z, a1.w, U1.u[3], U2.u[3]);
    A1 = U1.v; A2 = U2.v;
}

// ---- prep: weights + emb -> fragments in d_ws; also zeroes out_ld ----
// B-frag (16x16x32): lane holds B[k=(lane>>4)*8+j][n=lane&15] = W[n][k], j=0..7.
// emb A-frags: row n (task index), 3 levels x 16 packed-pair dwords.
__global__ void prep_weights(const float* __restrict__ W0, const float* __restrict__ W1,
                             const float* __restrict__ W2, const float* __restrict__ emb,
                             unsigned* __restrict__ ws, float* __restrict__ out_ld,
                             int do_emb) {
    int id = blockIdx.x * blockDim.x + threadIdx.x;
    if (id < kN) out_ld[id] = 0.f;                    // replaces hipMemsetAsync
    if (id < kPrepW) {
        int d = id / 9216, rem = id - d * 9216;
        unsigned* wd = ws + (size_t)d * kWsDwPerD;
        if (rem < 5120) {                              // forward bf16 3-level
            float x0, x1; unsigned o1, o2, o3;
            if (rem < 1024) {                          // W0 (K=32, 1 ktile)
                int idx = rem, j2 = idx & 3, ln = (idx >> 2) & 63, nt = (idx >> 8) & 3;
                int n_ = nt * 16 + (ln & 15), k_ = ((ln >> 4) << 3) + 2 * j2;
                const float* g = W0 + (size_t)d * kH * 33;
                x0 = g[n_ * 33 + k_]; x1 = g[n_ * 33 + k_ + 1];
                o1 = idx; o2 = 1024 + idx; o3 = 2048 + idx;
            } else if (rem < 3072) {                   // W1 (K=64, 2 ktiles)
                int idx = rem - 1024, j2 = idx & 3, ln = (idx >> 2) & 63;
                int kt = (idx >> 8) & 1, nt = (idx >> 9) & 3;
                int n_ = nt * 16 + (ln & 15), k_ = kt * 32 + ((ln >> 4) << 3) + 2 * j2;
                const float* g = W1 + (size_t)d * kH * kH;
                x0 = g[n_ * 64 + k_]; x1 = g[n_ * 64 + k_ + 1];
                o1 = 3072 + idx; o2 = 5120 + idx; o3 = 7168 + idx;
            } else {                                   // W2
                int idx = rem - 3072, j2 = idx & 3, ln = (idx >> 2) & 63;
                int kt = (idx >> 8) & 1, nt = (idx >> 9) & 3;
                int n_ = nt * 16 + (ln & 15), k_ = kt * 32 + ((ln >> 4) << 3) + 2 * j2;
                const float* g = W2 + (size_t)d * kH * kH;
                x0 = g[n_ * 64 + k_]; x1 = g[n_ * 64 + k_ + 1];
                o1 = 9216 + idx; o2 = 11264 + idx; o3 = 13312 + idx;
            }
            unsigned p1, p2, p3; split3_2(x0, x1, p1, p2, p3);
            wd[o1] = p1; wd[o2] = p2; wd[o3] = p3;
        } else {                                       // jacobian fp16 2-level
            int idx, base; const float* g;
            if (rem < 7168) { idx = rem - 5120; base = 15360; g = W1 + (size_t)d * kH * kH; }
            else            { idx = rem - 7168; base = 19456; g = W2 + (size_t)d * kH * kH; }
            int j2 = idx & 3, ln = (idx >> 2) & 63;
            int kt = (idx >> 8) & 1, nt = (idx >> 9) & 3;
            int n_ = nt * 16 + (ln & 15), k_ = kt * 32 + ((ln >> 4) << 3) + 2 * j2;
            float x0 = g[n_ * 64 + k_], x1 = g[n_ * 64 + k_ + 1];
            unsigned p1, p2; split2h(x0, x1, p1, p2);
            wd[base + idx] = p1; wd[base + 2048 + idx] = p2;
        }
    } else if (do_emb && id < kPrepW + kPrepE) {       // emb pre-split (RNE, once)
        int eid = id - kPrepW;
        int n = eid >> 4, p = eid & 15;                // pair p -> cols 2p, 2p+1
        int bb = n / kLen;
        size_t src = (size_t)(bb * kT + (n - bb * kLen) + 2);
        float x0 = emb[src * kE + 2 * p], x1 = emb[src * kE + 2 * p + 1];
        unsigned p1, p2, p3; split3_2(x0, x1, p1, p2, p3);
        unsigned* eb = ws + kWsEmbBase + (size_t)n * kEmbRowDw;
        eb[p] = p1; eb[16 + p] = p2; eb[32 + p] = p3;
    }
}

#define MFMA(A, B, C)  __builtin_amdgcn_mfma_f32_16x16x32_bf16((A), (B), (C), 0, 0, 0)
#define MFMAH(A, B, C) __builtin_amdgcn_mfma_f32_16x16x32_f16((A), (B), (C), 0, 0, 0)

// forward K=64 layer, 2 m-tiles: 6-product bf16x3, level-ordered (one B level live)
__device__ __forceinline__ void layer64_f(f32x4 acc[2][4],
                                          const float* r0, const float* r1,
                                          const unsigned* w1, const unsigned* w2,
                                          const unsigned* w3, int lane, int q) {
    #pragma unroll
    for (int kt = 0; kt < 2; ++kt) {
        bf16x8 A1[2], A2[2], A3[2];
        {
            const float4 a0 = *(const float4*)(r0 + kt * 32 + q * 8);
            const float4 a1 = *(const float4*)(r0 + kt * 32 + q * 8 + 4);
            splitA3t(a0, a1, A1[0], A2[0], A3[0]);
            const float4 b0_ = *(const float4*)(r1 + kt * 32 + q * 8);
            const float4 b1_ = *(const float4*)(r1 + kt * 32 + q * 8 + 4);
            splitA3t(b0_, b1_, A1[1], A2[1], A3[1]);
        }
        bf16x8 B[4];
        #pragma unroll
        for (int nt = 0; nt < 4; ++nt) B[nt] = *(const bf16x8*)(w1 + (((nt * 2 + kt) * 64 + lane) << 2));
        #pragma unroll
        for (int nt = 0; nt < 4; ++nt)
            #pragma unroll
            for (int mt = 0; mt < 2; ++mt) {
                acc[mt][nt] = MFMA(A3[mt], B[nt], acc[mt][nt]);
                acc[mt][nt] = MFMA(A2[mt], B[nt], acc[mt][nt]);
                acc[mt][nt] = MFMA(A1[mt], B[nt], acc[mt][nt]);
            }
        #pragma unroll
        for (int nt = 0; nt < 4; ++nt) B[nt] = *(const bf16x8*)(w2 + (((nt * 2 + kt) * 64 + lane) << 2));
        #pragma unroll
        for (int nt = 0; nt < 4; ++nt)
            #pragma unroll
            for (int mt = 0; mt < 2; ++mt) {
                acc[mt][nt] = MFMA(A2[mt], B[nt], acc[mt][nt]);
                acc[mt][nt] = MFMA(A1[mt], B[nt], acc[mt][nt]);
            }
        #pragma unroll
        for (int nt = 0; nt < 4; ++nt) B[nt] = *(const bf16x8*)(w3 + (((nt * 2 + kt) * 64 + lane) << 2));
        #pragma unroll
        for (int nt = 0; nt < 4; ++nt)
            #pragma unroll
            for (int mt = 0; mt < 2; ++mt)
                acc[mt][nt] = MFMA(A1[mt], B[nt], acc[mt][nt]);
    }
}

// Jacobian K=64 layer, 2 m-tiles: fp16 2-way split, 3 products (values only)
__device__ __forceinline__ void layer64_jh(f32x4 acc[2][4],
                                           const float* r0, const float* r1,
                                           const unsigned* wl1, const unsigned* wl2,
                                           int lane, int q) {
    #pragma unroll
    for (int kt = 0; kt < 2; ++kt) {
        f16x8 A1[2], A2[2];
        {
            const float4 a0 = *(const float4*)(r0 + kt * 32 + q * 8);
            const float4 a1 = *(const float4*)(r0 + kt * 32 + q * 8 + 4);
            splitA2h(a0, a1, A1[0], A2[0]);
            const float4 b0_ = *(const float4*)(r1 + kt * 32 + q * 8);
            const float4 b1_ = *(const float4*)(r1 + kt * 32 + q * 8 + 4);
            splitA2h(b0_, b1_, A1[1], A2[1]);
        }
        f16x8 B[4];
        #pragma unroll
        for (int nt = 0; nt < 4; ++nt) B[nt] = *(const f16x8*)(wl1 + (((nt * 2 + kt) * 64 + lane) << 2));
        #pragma unroll
        for (int nt = 0; nt < 4; ++nt)
            #pragma unroll
            for (int mt = 0; mt < 2; ++mt) {
                acc[mt][nt] = MFMAH(A2[mt], B[nt], acc[mt][nt]);
                acc[mt][nt] = MFMAH(A1[mt], B[nt], acc[mt][nt]);
            }
        #pragma unroll
        for (int nt = 0; nt < 4; ++nt) B[nt] = *(const f16x8*)(wl2 + (((nt * 2 + kt) * 64 + lane) << 2));
        #pragma unroll
        for (int nt = 0; nt < 4; ++nt)
            #pragma unroll
            for (int mt = 0; mt < 2; ++mt)
                acc[mt][nt] = MFMAH(A1[mt], B[nt], acc[mt][nt]);
    }
}

// Main: block = 128 threads = 2 waves; each wave owns 32 tasks (2 m-tiles of 16),
// all waves same d. C/D: task-row = mt*16 + (lane>>4)*4 + reg, unit = nt*16 + (lane&15).
// act rows carry layer boundaries; waves touch disjoint rows -> no barriers.
__global__ __launch_bounds__(128, 2) void np_mfma_kernel(
    const float* __restrict__ x, const float* __restrict__ emb,
    const float* __restrict__ W0, const float* __restrict__ b0,
    const float* __restrict__ b1, const float* __restrict__ b2,
    const float* __restrict__ Wo, const float* __restrict__ bo,
    const unsigned* __restrict__ ws, const unsigned* __restrict__ embws,
    float* __restrict__ out_res, float* __restrict__ out_ld)
{
    __shared__ __align__(16) float act[64 * AS];    // 17408 B

    const int tid  = threadIdx.x;
    const int lane = tid & 63;
    const int wave = __builtin_amdgcn_readfirstlane(tid >> 6);
    const int c = lane & 15, q = lane >> 4;
    const int tb = wave * 32;                        // block-local task base
    const int d  = blockIdx.y;
    const int nW = blockIdx.x * 64 + tb;             // global task base of wave

    // x for task nW + (q>>1)*16 + c  (64 lanes cover 32 tasks, 2-way redundant)
    const int nX  = nW + ((q >> 1) << 4) + c;
    const int bbX = nX / kLen;
    const float xm = x[((size_t)(bbX * kT + (nX - bbX * kLen) + 2)) * kD + d];
    float xr[2][4];
    #pragma unroll
    for (int mt = 0; mt < 2; ++mt)
        #pragma unroll
        for (int r = 0; r < 4; ++r)
            xr[mt][r] = __shfl(xm, mt * 32 + q * 4 + r, 64);  // src lane = 32*mt + row

    const float* W0g = W0 + (size_t)d * kH * 33;
    float b0v[4], wov[4], w0xv[4];
    #pragma unroll
    for (int nt = 0; nt < 4; ++nt) {
        const int u = nt * 16 + c;
        b0v[nt]  = b0[d * kH + u];
        wov[nt]  = Wo[d * kH + u];
        w0xv[nt] = W0g[u * 33 + 32];                 // last input column of W0
    }
    const float bov = bo[d];
    const unsigned* wd = ws + (size_t)d * kWsDwPerD;
    const float* r0 = &act[(tb + c) * AS];           // A rows for m-tile 0 / 1
    const float* r1 = &act[(tb + 16 + c) * AS];

    unsigned m0 = 0, m1 = 0, m2 = 0;                 // gate masks: bit = mt*16+nt*4+r
    f32x4 acc[2][4];

    // ---------- L0 (K=32): z0 = W0[:,:32]@emb + x*W0[:,32] + b0 ----------
    {
        bf16x8 A1[2], A2[2], A3[2];
        if (embws) {                                 // pre-split A-frags (fast path)
            #pragma unroll
            for (int mt = 0; mt < 2; ++mt) {
                const unsigned* eb = embws + (size_t)(nW + mt * 16 + c) * kEmbRowDw + q * 4;
                A1[mt] = *(const bf16x8*)(eb);
                A2[mt] = *(const bf16x8*)(eb + 16);
                A3[mt] = *(const bf16x8*)(eb + 32);
            }
        } else {                                     // fallback: inline split
            #pragma unroll
            for (int mt = 0; mt < 2; ++mt) {
                const int nA = nW + mt * 16 + c;
                const int bb = nA / kLen;
                const size_t src = (size_t)(bb * kT + (nA - bb * kLen) + 2);
                const float4* ep = (const float4*)(emb + src * kE + q * 8);
                splitA3t(ep[0], ep[1], A1[mt], A2[mt], A3[mt]);
            }
        }
        #pragma unroll
        for (int mt = 0; mt < 2; ++mt)
            #pragma unroll
            for (int nt = 0; nt < 4; ++nt) {
                f32x4 a;
                #pragma unroll
                for (int r = 0; r < 4; ++r) a[r] = fmaf(xr[mt][r], w0xv[nt], b0v[nt]);
                acc[mt][nt] = a;
            }
        bf16x8 B[4];
        #pragma unroll
        for (int nt = 0; nt < 4; ++nt) B[nt] = *(const bf16x8*)(wd + ((nt * 64 + lane) << 2));
        #pragma unroll
        for (int nt = 0; nt < 4; ++nt)
            #pragma unroll
            for (int mt = 0; mt < 2; ++mt) {
                acc[mt][nt] = MFMA(A3[mt], B[nt], acc[mt][nt]);
                acc[mt][nt] = MFMA(A2[mt], B[nt], acc[mt][nt]);
                acc[mt][nt] = MFMA(A1[mt], B[nt], acc[mt][nt]);
            }
        #pragma unroll
        for (int nt = 0; nt < 4; ++nt) B[nt] = *(const bf16x8*)(wd + 1024 + ((nt * 64 + lane) << 2));
        #pragma unroll
        for (int nt = 0; nt < 4; ++nt)
            #pragma unroll
            for (int mt = 0; mt < 2; ++mt) {
                acc[mt][nt] = MFMA(A2[mt], B[nt], acc[mt][nt]);
                acc[mt][nt] = MFMA(A1[mt], B[nt], acc[mt][nt]);
            }
        #pragma unroll
        for (int nt = 0; nt < 4; ++nt) B[nt] = *(const bf16x8*)(wd + 2048 + ((nt * 64 + lane) << 2));
        #pragma unroll
        for (int nt = 0; nt < 4; ++nt)
            #pragma unroll
            for (int mt = 0; mt < 2; ++mt)
                acc[mt][nt] = MFMA(A1[mt], B[nt], acc[mt][nt]);
        #pragma unroll
        for (int mt = 0; mt < 2; ++mt)
            #pragma unroll
            for (int nt = 0; nt < 4; ++nt)
                #pragma unroll
                for (int r = 0; r < 4; ++r) {
                    float z = acc[mt][nt][r];
                    m0 |= (unsigned)(z >= 0.f) << (mt * 16 + nt * 4 + r);
                    act[(tb + mt * 16 + q * 4 + r) * AS + nt * 16 + c] = fmaxf(z, z * kSlope);
                }
    }

    // ---------- L1 ----------
    {
        #pragma unroll
        for (int nt = 0; nt < 4; ++nt) {
            const float bv = b1[d * kH + nt * 16 + c];
            #pragma unroll
            for (int mt = 0; mt < 2; ++mt) {
                f32x4 a;
                #pragma unroll
                for (int r = 0; r < 4; ++r) a[r] = bv;
                acc[mt][nt] = a;
            }
        }
        layer64_f(acc, r0, r1, wd + 3072, wd + 5120, wd + 7168, lane, q);
        #pragma unroll
        for (int mt = 0; mt < 2; ++mt)
            #pragma unroll
            for (int nt = 0; nt < 4; ++nt)
                #pragma unroll
                for (int r = 0; r < 4; ++r) {
                    float z = acc[mt][nt][r];
                    m1 |= (unsigned)(z >= 0.f) << (mt * 16 + nt * 4 + r);
                    act[(tb + mt * 16 + q * 4 + r) * AS + nt * 16 + c] = fmaxf(z, z * kSlope);
                }
    }

    // ---------- L2 + fused forward head ----------
    {
        #pragma unroll
        for (int nt = 0; nt < 4; ++nt) {
            const float bv = b2[d * kH + nt * 16 + c];
            #pragma unroll
            for (int mt = 0; mt < 2; ++mt) {
                f32x4 a;
                #pragma unroll
                for (int r = 0; r < 4; ++r) a[r] = bv;
                acc[mt][nt] = a;
            }
        }
        layer64_f(acc, r0, r1, wd + 9216, wd + 11264, wd + 13312, lane, q);
        float pr[2][4] = {{0.f,0.f,0.f,0.f},{0.f,0.f,0.f,0.f}};
        #pragma unroll
        for (int mt = 0; mt < 2; ++mt)
            #pragma unroll
            for (int nt = 0; nt < 4; ++nt)
                #pragma unroll
                for (int r = 0; r < 4; ++r) {
                    float z = acc[mt][nt][r];
                    m2 |= (unsigned)(z >= 0.f) << (mt * 16 + nt * 4 + r);
                    pr[mt][r] = fmaf(wov[nt], fmaxf(z, z * kSlope), pr[mt][r]);
                }
        #pragma unroll
        for (int mt = 0; mt < 2; ++mt)
            #pragma unroll
            for (int r = 0; r < 4; ++r) {
                #pragma unroll
                for (int s = 1; s < 16; s <<= 1) pr[mt][r] += __shfl_xor(pr[mt][r], s, 16);
            }
        if (c == 0) {
            #pragma unroll
            for (int mt = 0; mt < 2; ++mt)
                #pragma unroll
                for (int r = 0; r < 4; ++r)
                    out_res[(size_t)(nW + mt * 16 + q * 4 + r) * kD + d] = pr[mt][r] + bov;
        }
    }

    // ---------- Jacobian t0 = g0 * W0[:, 32] ----------
    #pragma unroll
    for (int mt = 0; mt < 2; ++mt)
        #pragma unroll
        for (int nt = 0; nt < 4; ++nt)
            #pragma unroll
            for (int r = 0; r < 4; ++r)
                act[(tb + mt * 16 + q * 4 + r) * AS + nt * 16 + c] =
                    (((m0 >> (mt * 16 + nt * 4 + r)) & 1u) ? 1.f : kSlope) * w0xv[nt];

    // ---------- jac L1: t1 = g1 * (W1 @ t0)  [fp16 2-way, 3 products] ----------
    {
        #pragma unroll
        for (int mt = 0; mt < 2; ++mt)
            #pragma unroll
            for (int nt = 0; nt < 4; ++nt) acc[mt][nt] = (f32x4){0.f, 0.f, 0.f, 0.f};
        layer64_jh(acc, r0, r1, wd + 15360, wd + 17408, lane, q);
        #pragma unroll
        for (int mt = 0; mt < 2; ++mt)
            #pragma unroll
            for (int nt = 0; nt < 4; ++nt)
                #pragma unroll
                for (int r = 0; r < 4; ++r)
                    act[(tb + mt * 16 + q * 4 + r) * AS + nt * 16 + c] =
                        (((m1 >> (mt * 16 + nt * 4 + r)) & 1u) ? 1.f : kSlope) * acc[mt][nt][r];
    }

    // ---------- jac L2 + fused Jacobian head ----------
    {
        #pragma unroll
        for (int mt = 0; mt < 2; ++mt)
            #pragma unroll
            for (int nt = 0; nt < 4; ++nt) acc[mt][nt] = (f32x4){0.f, 0.f, 0.f, 0.f};
        layer64_jh(acc, r0, r1, wd + 19456, wd + 21504, lane, q);
        float pr[2][4] = {{0.f,0.f,0.f,0.f},{0.f,0.f,0.f,0.f}};
        #pragma unroll
        for (int mt = 0; mt < 2; ++mt)
            #pragma unroll
            for (int nt = 0; nt < 4; ++nt)
                #pragma unroll
                for (int r = 0; r < 4; ++r) {
                    float t = (((m2 >> (mt * 16 + nt * 4 + r)) & 1u) ? 1.f : kSlope) * acc[mt][nt][r];
                    pr[mt][r] = fmaf(wov[nt], t, pr[mt][r]);
                }
        #pragma unroll
        for (int mt = 0; mt < 2; ++mt)
            #pragma unroll
            for (int r = 0; r < 4; ++r) {
                #pragma unroll
                for (int s = 1; s < 16; s <<= 1) pr[mt][r] += __shfl_xor(pr[mt][r], s, 16);
            }
        if (c == 0) {
            #pragma unroll
            for (int mt = 0; mt < 2; ++mt)
                #pragma unroll
                for (int r = 0; r < 4; ++r)
                    atomicAdd(&out_ld[nW + mt * 16 + q * 4 + r], __logf(fabsf(pr[mt][r])));
        }
    }
}

extern "C" void kernel_launch(void* const* d_in, const int* in_sizes, int n_in,
                              void* d_out, int out_size, void* d_ws, size_t ws_size,
                              hipStream_t stream) {
    const float* x  = (const float*)d_in[0];
    const float* em = (const float*)d_in[1];
    const float* W0 = (const float*)d_in[2];
    const float* b0 = (const float*)d_in[3];
    const float* W1 = (const float*)d_in[4];
    const float* b1 = (const float*)d_in[5];
    const float* W2 = (const float*)d_in[6];
    const float* b2 = (const float*)d_in[7];
    const float* Wo = (const float*)d_in[8];
    const float* bo = (const float*)d_in[9];

    float* out_res = (float*)d_out;                    // [N, D] residuals
    float* out_ld  = (float*)d_out + (size_t)kN * kD;  // [N] log|det J|
    unsigned* ws   = (unsigned*)d_ws;

    const size_t needed = (size_t)(kWsEmbBase + kWsEmbDw) * 4;   // ~7.65 MB
    const bool big = ws_size >= needed;
    const unsigned* embws = big ? ws + kWsEmbBase : nullptr;

    const int prep_items = big ? (kPrepW + kPrepE) : kPrepW;
    prep_weights<<<dim3((prep_items + 255) / 256), dim3(256), 0, stream>>>(
        W0, W1, W2, em, ws, out_ld, big ? 1 : 0);
    np_mfma_kernel<<<dim3(kN / 64, kD), dim3(128), 0, stream>>>(
        x, em, W0, b0, b1, b2, Wo, bo, ws, embws, out_res, out_ld);
}

// Round 13
// 182.046 us; speedup vs baseline: 1.0883x; 1.0883x over previous
//
#include <hip/hip_runtime.h>

// ---- problem constants ----
constexpr int   kT    = 1002;
constexpr int   kD    = 16;
constexpr int   kE    = 32;
constexpr int   kH    = 64;
constexpr int   kLen  = kT - 2;     // 1000
constexpr int   kN    = 32 * kLen;  // 32000
constexpr float kSlope = 0.2f;
constexpr int   AS    = 68;         // act row stride (floats)
// per-d ws dwords: fwd bf16 3-level (w0 3*1024 @0, w1 3*2048 @3072, w2 3*2048 @9216),
// jac fp16 2-level (w1 @15360/17408, w2 @19456/21504)
constexpr int   kWsDwPerD = 23552;

typedef __attribute__((ext_vector_type(8))) short bf16x8;
typedef __attribute__((ext_vector_type(4))) float f32x4;
typedef __attribute__((ext_vector_type(2))) __fp16 fp16x2;     // cvt_pkrtz result type
typedef __attribute__((ext_vector_type(8))) _Float16 f16x8;    // MFMA f16 operand type

// ---------------- bf16 splits ----------------
// RNE pair-round (full accuracy — used in prep where it's free)
__device__ __forceinline__ unsigned rne2(float x0, float x1, float &h0, float &h1) {
    unsigned u0 = __float_as_uint(x0), u1 = __float_as_uint(x1);
    unsigned r0 = u0 + 0x7FFFu + ((u0 >> 16) & 1u);
    unsigned r1 = u1 + 0x7FFFu + ((u1 >> 16) & 1u);
    h0 = __uint_as_float(r0 & 0xFFFF0000u);
    h1 = __uint_as_float(r1 & 0xFFFF0000u);
    return __builtin_amdgcn_perm(r1, r0, 0x07060302u);  // [r0.hi16 | r1.hi16<<16]
}

// truncation pair-round (cheap — 3 ops): h = x with low 16 bits cleared (exact x-h)
__device__ __forceinline__ unsigned trunc2(float x0, float x1, float &h0, float &h1) {
    unsigned u0 = __float_as_uint(x0), u1 = __float_as_uint(x1);
    h0 = __uint_as_float(u0 & 0xFFFF0000u);
    h1 = __uint_as_float(u1 & 0xFFFF0000u);
    return __builtin_amdgcn_perm(u1, u0, 0x07060302u);
}

// full-RNE 3-way split (prep: weights)
__device__ __forceinline__ void split3_2(float x0, float x1,
                                         unsigned &p1, unsigned &p2, unsigned &p3) {
    float h0, h1; p1 = rne2(x0, x1, h0, h1);
    float e0 = x0 - h0, e1 = x1 - h1;      // exact
    float m0, m1; p2 = rne2(e0, e1, m0, m1);
    float f0 = e0 - m0, f1 = e1 - m1;      // exact
    float t0, t1; p3 = rne2(f0, f1, t0, t1);
}

// trunc-trunc-RNE 3-way split (main-kernel act/emb splits). Only the LAST level's
// rounding survives as representation error (e1,e2 exact fp32 subtractions), so
// this is ~2x all-RNE (2^-25 vs 2^-26 rel) at 15 vs 23 VALU ops/pair.
// Validated round 12: absmax 1.0.
__device__ __forceinline__ void split3t_2(float x0, float x1,
                                          unsigned &p1, unsigned &p2, unsigned &p3) {
    float h0, h1; p1 = trunc2(x0, x1, h0, h1);
    float e0 = x0 - h0, e1 = x1 - h1;      // exact
    float m0, m1; p2 = trunc2(e0, e1, m0, m1);
    float f0 = e0 - m0, f1 = e1 - m1;      // exact
    float t0, t1; p3 = rne2(f0, f1, t0, t1);   // h outputs DCE'd
}

union FragU { unsigned u[4]; bf16x8 v; };

__device__ __forceinline__ void splitA3t(const float4 a0, const float4 a1,
                                         bf16x8 &A1, bf16x8 &A2, bf16x8 &A3) {
    FragU U1, U2, U3;
    split3t_2(a0.x, a0.y, U1.u[0], U2.u[0], U3.u[0]);
    split3t_2(a0.z, a0.w, U1.u[1], U2.u[1], U3.u[1]);
    split3t_2(a1.x, a1.y, U1.u[2], U2.u[2], U3.u[2]);
    split3t_2(a1.z, a1.w, U1.u[3], U2.u[3], U3.u[3]);
    A1 = U1.v; A2 = U2.v; A3 = U3.v;
}

// ---------------- fp16 splits (Jacobian path: values only, ~21-bit) ----------------
__device__ __forceinline__ void split2h(float x0, float x1, unsigned &p1, unsigned &p2) {
    fp16x2 h = __builtin_amdgcn_cvt_pkrtz(x0, x1);
    __builtin_memcpy(&p1, &h, 4);
    fp16x2 l = __builtin_amdgcn_cvt_pkrtz(x0 - (float)h[0], x1 - (float)h[1]);
    __builtin_memcpy(&p2, &l, 4);
}

union FragH { unsigned u[4]; f16x8 v; };

__device__ __forceinline__ void splitA2h(const float4 a0, const float4 a1,
                                         f16x8 &A1, f16x8 &A2) {
    FragH U1, U2;
    split2h(a0.x, a0.y, U1.u[0], U2.u[0]);
    split2h(a0.z, a0.w, U1.u[1], U2.u[1]);
    split2h(a1.x, a1.y, U1.u[2], U2.u[2]);
    split2h(a1.z, a1.w, U1.u[3], U2.u[3]);
    A1 = U1.v; A2 = U2.v;
}

// ---- prep: weights -> B-fragments in d_ws; also zeroes out_ld ----
// B-frag (16x16x32): lane holds B[k=(lane>>4)*8+j][n=lane&15] = W[n][k], j=0..7.
__global__ void prep_weights(const float* __restrict__ W0, const float* __restrict__ W1,
                             const float* __restrict__ W2, unsigned* __restrict__ ws,
                             float* __restrict__ out_ld) {
    int id = blockIdx.x * blockDim.x + threadIdx.x;   // 16*9216 total
    if (id < kN) out_ld[id] = 0.f;                    // replaces hipMemsetAsync
    if (id >= 16 * 9216) return;
    int d = id / 9216, rem = id - d * 9216;
    unsigned* wd = ws + (size_t)d * kWsDwPerD;

    if (rem < 5120) {                                  // forward bf16 3-level
        float x0, x1; unsigned o1, o2, o3;
        if (rem < 1024) {                              // W0 (K=32, 1 ktile)
            int idx = rem, j2 = idx & 3, ln = (idx >> 2) & 63, nt = (idx >> 8) & 3;
            int n_ = nt * 16 + (ln & 15), k_ = ((ln >> 4) << 3) + 2 * j2;
            const float* g = W0 + (size_t)d * kH * 33;
            x0 = g[n_ * 33 + k_]; x1 = g[n_ * 33 + k_ + 1];
            o1 = idx; o2 = 1024 + idx; o3 = 2048 + idx;
        } else if (rem < 3072) {                       // W1 (K=64, 2 ktiles)
            int idx = rem - 1024, j2 = idx & 3, ln = (idx >> 2) & 63;
            int kt = (idx >> 8) & 1, nt = (idx >> 9) & 3;
            int n_ = nt * 16 + (ln & 15), k_ = kt * 32 + ((ln >> 4) << 3) + 2 * j2;
            const float* g = W1 + (size_t)d * kH * kH;
            x0 = g[n_ * 64 + k_]; x1 = g[n_ * 64 + k_ + 1];
            o1 = 3072 + idx; o2 = 5120 + idx; o3 = 7168 + idx;
        } else {                                       // W2
            int idx = rem - 3072, j2 = idx & 3, ln = (idx >> 2) & 63;
            int kt = (idx >> 8) & 1, nt = (idx >> 9) & 3;
            int n_ = nt * 16 + (ln & 15), k_ = kt * 32 + ((ln >> 4) << 3) + 2 * j2;
            const float* g = W2 + (size_t)d * kH * kH;
            x0 = g[n_ * 64 + k_]; x1 = g[n_ * 64 + k_ + 1];
            o1 = 9216 + idx; o2 = 11264 + idx; o3 = 13312 + idx;
        }
        unsigned p1, p2, p3; split3_2(x0, x1, p1, p2, p3);
        wd[o1] = p1; wd[o2] = p2; wd[o3] = p3;
    } else {                                           // jacobian fp16 2-level
        int idx, base; const float* g;
        if (rem < 7168) { idx = rem - 5120; base = 15360; g = W1 + (size_t)d * kH * kH; }
        else            { idx = rem - 7168; base = 19456; g = W2 + (size_t)d * kH * kH; }
        int j2 = idx & 3, ln = (idx >> 2) & 63;
        int kt = (idx >> 8) & 1, nt = (idx >> 9) & 3;
        int n_ = nt * 16 + (ln & 15), k_ = kt * 32 + ((ln >> 4) << 3) + 2 * j2;
        float x0 = g[n_ * 64 + k_], x1 = g[n_ * 64 + k_ + 1];
        unsigned p1, p2; split2h(x0, x1, p1, p2);
        wd[base + idx] = p1; wd[base + 2048 + idx] = p2;
    }
}

#define MFMA(A, B, C)  __builtin_amdgcn_mfma_f32_16x16x32_bf16((A), (B), (C), 0, 0, 0)
#define MFMAH(A, B, C) __builtin_amdgcn_mfma_f32_16x16x32_f16((A), (B), (C), 0, 0, 0)

// forward K=64 layer, 2 m-tiles: 6-product bf16x3, level-ordered (one B level live)
__device__ __forceinline__ void layer64_f(f32x4 acc[2][4],
                                          const float* r0, const float* r1,
                                          const unsigned* w1, const unsigned* w2,
                                          const unsigned* w3, int lane, int q) {
    #pragma unroll
    for (int kt = 0; kt < 2; ++kt) {
        bf16x8 A1[2], A2[2], A3[2];
        {
            const float4 a0 = *(const float4*)(r0 + kt * 32 + q * 8);
            const float4 a1 = *(const float4*)(r0 + kt * 32 + q * 8 + 4);
            splitA3t(a0, a1, A1[0], A2[0], A3[0]);
            const float4 b0_ = *(const float4*)(r1 + kt * 32 + q * 8);
            const float4 b1_ = *(const float4*)(r1 + kt * 32 + q * 8 + 4);
            splitA3t(b0_, b1_, A1[1], A2[1], A3[1]);
        }
        bf16x8 B[4];
        #pragma unroll
        for (int nt = 0; nt < 4; ++nt) B[nt] = *(const bf16x8*)(w1 + (((nt * 2 + kt) * 64 + lane) << 2));
        #pragma unroll
        for (int nt = 0; nt < 4; ++nt)
            #pragma unroll
            for (int mt = 0; mt < 2; ++mt) {
                acc[mt][nt] = MFMA(A3[mt], B[nt], acc[mt][nt]);
                acc[mt][nt] = MFMA(A2[mt], B[nt], acc[mt][nt]);
                acc[mt][nt] = MFMA(A1[mt], B[nt], acc[mt][nt]);
            }
        #pragma unroll
        for (int nt = 0; nt < 4; ++nt) B[nt] = *(const bf16x8*)(w2 + (((nt * 2 + kt) * 64 + lane) << 2));
        #pragma unroll
        for (int nt = 0; nt < 4; ++nt)
            #pragma unroll
            for (int mt = 0; mt < 2; ++mt) {
                acc[mt][nt] = MFMA(A2[mt], B[nt], acc[mt][nt]);
                acc[mt][nt] = MFMA(A1[mt], B[nt], acc[mt][nt]);
            }
        #pragma unroll
        for (int nt = 0; nt < 4; ++nt) B[nt] = *(const bf16x8*)(w3 + (((nt * 2 + kt) * 64 + lane) << 2));
        #pragma unroll
        for (int nt = 0; nt < 4; ++nt)
            #pragma unroll
            for (int mt = 0; mt < 2; ++mt)
                acc[mt][nt] = MFMA(A1[mt], B[nt], acc[mt][nt]);
    }
}

// Jacobian K=64 layer, 2 m-tiles: fp16 2-way split, 3 products (values only)
__device__ __forceinline__ void layer64_jh(f32x4 acc[2][4],
                                           const float* r0, const float* r1,
                                           const unsigned* wl1, const unsigned* wl2,
                                           int lane, int q) {
    #pragma unroll
    for (int kt = 0; kt < 2; ++kt) {
        f16x8 A1[2], A2[2];
        {
            const float4 a0 = *(const float4*)(r0 + kt * 32 + q * 8);
            const float4 a1 = *(const float4*)(r0 + kt * 32 + q * 8 + 4);
            splitA2h(a0, a1, A1[0], A2[0]);
            const float4 b0_ = *(const float4*)(r1 + kt * 32 + q * 8);
            const float4 b1_ = *(const float4*)(r1 + kt * 32 + q * 8 + 4);
            splitA2h(b0_, b1_, A1[1], A2[1]);
        }
        f16x8 B[4];
        #pragma unroll
        for (int nt = 0; nt < 4; ++nt) B[nt] = *(const f16x8*)(wl1 + (((nt * 2 + kt) * 64 + lane) << 2));
        #pragma unroll
        for (int nt = 0; nt < 4; ++nt)
            #pragma unroll
            for (int mt = 0; mt < 2; ++mt) {
                acc[mt][nt] = MFMAH(A2[mt], B[nt], acc[mt][nt]);
                acc[mt][nt] = MFMAH(A1[mt], B[nt], acc[mt][nt]);
            }
        #pragma unroll
        for (int nt = 0; nt < 4; ++nt) B[nt] = *(const f16x8*)(wl2 + (((nt * 2 + kt) * 64 + lane) << 2));
        #pragma unroll
        for (int nt = 0; nt < 4; ++nt)
            #pragma unroll
            for (int mt = 0; mt < 2; ++mt)
                acc[mt][nt] = MFMAH(A1[mt], B[nt], acc[mt][nt]);
    }
}

// Main: block = 128 threads = 2 waves; each wave owns 32 tasks (2 m-tiles of 16),
// all waves same d. C/D: task-row = mt*16 + (lane>>4)*4 + reg, unit = nt*16 + (lane&15).
// act rows carry layer boundaries; waves touch disjoint rows -> no barriers.
// NOTE (round-12 post-mortem): do NOT pre-split emb into global ws — it trades
// latency-hidden VALU for an exposed global-load chain in L0 (125->137 µs).
__global__ __launch_bounds__(128, 2) void np_mfma_kernel(
    const float* __restrict__ x, const float* __restrict__ emb,
    const float* __restrict__ W0, const float* __restrict__ b0,
    const float* __restrict__ b1, const float* __restrict__ b2,
    const float* __restrict__ Wo, const float* __restrict__ bo,
    const unsigned* __restrict__ ws,
    float* __restrict__ out_res, float* __restrict__ out_ld)
{
    __shared__ __align__(16) float act[64 * AS];    // 17408 B

    const int tid  = threadIdx.x;
    const int lane = tid & 63;
    const int wave = __builtin_amdgcn_readfirstlane(tid >> 6);
    const int c = lane & 15, q = lane >> 4;
    const int tb = wave * 32;                        // block-local task base
    const int d  = blockIdx.y;
    const int nW = blockIdx.x * 64 + tb;             // global task base of wave

    // x for task nW + (q>>1)*16 + c  (64 lanes cover 32 tasks, 2-way redundant)
    const int nX  = nW + ((q >> 1) << 4) + c;
    const int bbX = nX / kLen;
    const float xm = x[((size_t)(bbX * kT + (nX - bbX * kLen) + 2)) * kD + d];
    float xr[2][4];
    #pragma unroll
    for (int mt = 0; mt < 2; ++mt)
        #pragma unroll
        for (int r = 0; r < 4; ++r)
            xr[mt][r] = __shfl(xm, mt * 32 + q * 4 + r, 64);  // src lane = 32*mt + row

    const float* W0g = W0 + (size_t)d * kH * 33;
    float b0v[4], wov[4], w0xv[4];
    #pragma unroll
    for (int nt = 0; nt < 4; ++nt) {
        const int u = nt * 16 + c;
        b0v[nt]  = b0[d * kH + u];
        wov[nt]  = Wo[d * kH + u];
        w0xv[nt] = W0g[u * 33 + 32];                 // last input column of W0
    }
    const float bov = bo[d];
    const unsigned* wd = ws + (size_t)d * kWsDwPerD;
    const float* r0 = &act[(tb + c) * AS];           // A rows for m-tile 0 / 1
    const float* r1 = &act[(tb + 16 + c) * AS];

    unsigned m0 = 0, m1 = 0, m2 = 0;                 // gate masks: bit = mt*16+nt*4+r
    f32x4 acc[2][4];

    // ---------- L0 (K=32): z0 = W0[:,:32]@emb + x*W0[:,32] + b0 ----------
    {
        bf16x8 A1[2], A2[2], A3[2];
        #pragma unroll
        for (int mt = 0; mt < 2; ++mt) {
            const int nA = nW + mt * 16 + c;
            const int bb = nA / kLen;
            const size_t src = (size_t)(bb * kT + (nA - bb * kLen) + 2);
            const float4* ep = (const float4*)(emb + src * kE + q * 8);
            splitA3t(ep[0], ep[1], A1[mt], A2[mt], A3[mt]);
        }
        #pragma unroll
        for (int mt = 0; mt < 2; ++mt)
            #pragma unroll
            for (int nt = 0; nt < 4; ++nt) {
                f32x4 a;
                #pragma unroll
                for (int r = 0; r < 4; ++r) a[r] = fmaf(xr[mt][r], w0xv[nt], b0v[nt]);
                acc[mt][nt] = a;
            }
        bf16x8 B[4];
        #pragma unroll
        for (int nt = 0; nt < 4; ++nt) B[nt] = *(const bf16x8*)(wd + ((nt * 64 + lane) << 2));
        #pragma unroll
        for (int nt = 0; nt < 4; ++nt)
            #pragma unroll
            for (int mt = 0; mt < 2; ++mt) {
                acc[mt][nt] = MFMA(A3[mt], B[nt], acc[mt][nt]);
                acc[mt][nt] = MFMA(A2[mt], B[nt], acc[mt][nt]);
                acc[mt][nt] = MFMA(A1[mt], B[nt], acc[mt][nt]);
            }
        #pragma unroll
        for (int nt = 0; nt < 4; ++nt) B[nt] = *(const bf16x8*)(wd + 1024 + ((nt * 64 + lane) << 2));
        #pragma unroll
        for (int nt = 0; nt < 4; ++nt)
            #pragma unroll
            for (int mt = 0; mt < 2; ++mt) {
                acc[mt][nt] = MFMA(A2[mt], B[nt], acc[mt][nt]);
                acc[mt][nt] = MFMA(A1[mt], B[nt], acc[mt][nt]);
            }
        #pragma unroll
        for (int nt = 0; nt < 4; ++nt) B[nt] = *(const bf16x8*)(wd + 2048 + ((nt * 64 + lane) << 2));
        #pragma unroll
        for (int nt = 0; nt < 4; ++nt)
            #pragma unroll
            for (int mt = 0; mt < 2; ++mt)
                acc[mt][nt] = MFMA(A1[mt], B[nt], acc[mt][nt]);
        #pragma unroll
        for (int mt = 0; mt < 2; ++mt)
            #pragma unroll
            for (int nt = 0; nt < 4; ++nt)
                #pragma unroll
                for (int r = 0; r < 4; ++r) {
                    float z = acc[mt][nt][r];
                    m0 |= (unsigned)(z >= 0.f) << (mt * 16 + nt * 4 + r);
                    act[(tb + mt * 16 + q * 4 + r) * AS + nt * 16 + c] = fmaxf(z, z * kSlope);
                }
    }

    // ---------- L1 ----------
    {
        #pragma unroll
        for (int nt = 0; nt < 4; ++nt) {
            const float bv = b1[d * kH + nt * 16 + c];
            #pragma unroll
            for (int mt = 0; mt < 2; ++mt) {
                f32x4 a;
                #pragma unroll
                for (int r = 0; r < 4; ++r) a[r] = bv;
                acc[mt][nt] = a;
            }
        }
        layer64_f(acc, r0, r1, wd + 3072, wd + 5120, wd + 7168, lane, q);
        #pragma unroll
        for (int mt = 0; mt < 2; ++mt)
            #pragma unroll
            for (int nt = 0; nt < 4; ++nt)
                #pragma unroll
                for (int r = 0; r < 4; ++r) {
                    float z = acc[mt][nt][r];
                    m1 |= (unsigned)(z >= 0.f) << (mt * 16 + nt * 4 + r);
                    act[(tb + mt * 16 + q * 4 + r) * AS + nt * 16 + c] = fmaxf(z, z * kSlope);
                }
    }

    // ---------- L2 + fused forward head ----------
    {
        #pragma unroll
        for (int nt = 0; nt < 4; ++nt) {
            const float bv = b2[d * kH + nt * 16 + c];
            #pragma unroll
            for (int mt = 0; mt < 2; ++mt) {
                f32x4 a;
                #pragma unroll
                for (int r = 0; r < 4; ++r) a[r] = bv;
                acc[mt][nt] = a;
            }
        }
        layer64_f(acc, r0, r1, wd + 9216, wd + 11264, wd + 13312, lane, q);
        float pr[2][4] = {{0.f,0.f,0.f,0.f},{0.f,0.f,0.f,0.f}};
        #pragma unroll
        for (int mt = 0; mt < 2; ++mt)
            #pragma unroll
            for (int nt = 0; nt < 4; ++nt)
                #pragma unroll
                for (int r = 0; r < 4; ++r) {
                    float z = acc[mt][nt][r];
                    m2 |= (unsigned)(z >= 0.f) << (mt * 16 + nt * 4 + r);
                    pr[mt][r] = fmaf(wov[nt], fmaxf(z, z * kSlope), pr[mt][r]);
                }
        #pragma unroll
        for (int mt = 0; mt < 2; ++mt)
            #pragma unroll
            for (int r = 0; r < 4; ++r) {
                #pragma unroll
                for (int s = 1; s < 16; s <<= 1) pr[mt][r] += __shfl_xor(pr[mt][r], s, 16);
            }
        if (c == 0) {
            #pragma unroll
            for (int mt = 0; mt < 2; ++mt)
                #pragma unroll
                for (int r = 0; r < 4; ++r)
                    out_res[(size_t)(nW + mt * 16 + q * 4 + r) * kD + d] = pr[mt][r] + bov;
        }
    }

    // ---------- Jacobian t0 = g0 * W0[:, 32] ----------
    #pragma unroll
    for (int mt = 0; mt < 2; ++mt)
        #pragma unroll
        for (int nt = 0; nt < 4; ++nt)
            #pragma unroll
            for (int r = 0; r < 4; ++r)
                act[(tb + mt * 16 + q * 4 + r) * AS + nt * 16 + c] =
                    (((m0 >> (mt * 16 + nt * 4 + r)) & 1u) ? 1.f : kSlope) * w0xv[nt];

    // ---------- jac L1: t1 = g1 * (W1 @ t0)  [fp16 2-way, 3 products] ----------
    {
        #pragma unroll
        for (int mt = 0; mt < 2; ++mt)
            #pragma unroll
            for (int nt = 0; nt < 4; ++nt) acc[mt][nt] = (f32x4){0.f, 0.f, 0.f, 0.f};
        layer64_jh(acc, r0, r1, wd + 15360, wd + 17408, lane, q);
        #pragma unroll
        for (int mt = 0; mt < 2; ++mt)
            #pragma unroll
            for (int nt = 0; nt < 4; ++nt)
                #pragma unroll
                for (int r = 0; r < 4; ++r)
                    act[(tb + mt * 16 + q * 4 + r) * AS + nt * 16 + c] =
                        (((m1 >> (mt * 16 + nt * 4 + r)) & 1u) ? 1.f : kSlope) * acc[mt][nt][r];
    }

    // ---------- jac L2 + fused Jacobian head ----------
    {
        #pragma unroll
        for (int mt = 0; mt < 2; ++mt)
            #pragma unroll
            for (int nt = 0; nt < 4; ++nt) acc[mt][nt] = (f32x4){0.f, 0.f, 0.f, 0.f};
        layer64_jh(acc, r0, r1, wd + 19456, wd + 21504, lane, q);
        float pr[2][4] = {{0.f,0.f,0.f,0.f},{0.f,0.f,0.f,0.f}};
        #pragma unroll
        for (int mt = 0; mt < 2; ++mt)
            #pragma unroll
            for (int nt = 0; nt < 4; ++nt)
                #pragma unroll
                for (int r = 0; r < 4; ++r) {
                    float t = (((m2 >> (mt * 16 + nt * 4 + r)) & 1u) ? 1.f : kSlope) * acc[mt][nt][r];
                    pr[mt][r] = fmaf(wov[nt], t, pr[mt][r]);
                }
        #pragma unroll
        for (int mt = 0; mt < 2; ++mt)
            #pragma unroll
            for (int r = 0; r < 4; ++r) {
                #pragma unroll
                for (int s = 1; s < 16; s <<= 1) pr[mt][r] += __shfl_xor(pr[mt][r], s, 16);
            }
        if (c == 0) {
            #pragma unroll
            for (int mt = 0; mt < 2; ++mt)
                #pragma unroll
                for (int r = 0; r < 4; ++r)
                    atomicAdd(&out_ld[nW + mt * 16 + q * 4 + r], __logf(fabsf(pr[mt][r])));
        }
    }
}

extern "C" void kernel_launch(void* const* d_in, const int* in_sizes, int n_in,
                              void* d_out, int out_size, void* d_ws, size_t ws_size,
                              hipStream_t stream) {
    const float* x  = (const float*)d_in[0];
    const float* em = (const float*)d_in[1];
    const float* W0 = (const float*)d_in[2];
    const float* b0 = (const float*)d_in[3];
    const float* W1 = (const float*)d_in[4];
    const float* b1 = (const float*)d_in[5];
    const float* W2 = (const float*)d_in[6];
    const float* b2 = (const float*)d_in[7];
    const float* Wo = (const float*)d_in[8];
    const float* bo = (const float*)d_in[9];

    float* out_res = (float*)d_out;                    // [N, D] residuals
    float* out_ld  = (float*)d_out + (size_t)kN * kD;  // [N] log|det J|
    unsigned* ws   = (unsigned*)d_ws;                  // 1,507,328 B of weight frags

    prep_weights<<<dim3(16 * 9216 / 256), dim3(256), 0, stream>>>(W0, W1, W2, ws, out_ld);
    np_mfma_kernel<<<dim3(kN / 64, kD), dim3(128), 0, stream>>>(
        x, em, W0, b0, b1, b2, Wo, bo, ws, out_res, out_ld);
}

// Round 15
// 177.590 us; speedup vs baseline: 1.1156x; 1.0251x over previous
//
#include <hip/hip_runtime.h>

// ---- problem constants ----
constexpr int   kT    = 1002;
constexpr int   kD    = 16;
constexpr int   kE    = 32;
constexpr int   kH    = 64;
constexpr int   kLen  = kT - 2;     // 1000
constexpr int   kN    = 32 * kLen;  // 32000
constexpr float kSlope = 0.2f;
constexpr int   AS    = 68;         // act row stride (floats)
// per-d ws dwords: fwd bf16 3-level (w0 3*1024 @0, w1 3*2048 @3072, w2 3*2048 @9216),
// jac fp16 2-level (w1 @15360/17408, w2 @19456/21504)
constexpr int   kWsDwPerD = 23552;

typedef __attribute__((ext_vector_type(8))) short bf16x8;
typedef __attribute__((ext_vector_type(4))) float f32x4;
typedef __attribute__((ext_vector_type(2))) __fp16 fp16x2;     // cvt_pkrtz result type
typedef __attribute__((ext_vector_type(8))) _Float16 f16x8;    // MFMA f16 operand type

// ---------------- bf16 splits ----------------
// NUMERICS MAP (rounds 6/14 post-mortems):
//  - forward gates need ~2^-24 z-accuracy -> bf16 3-level, 6 products. 2-level
//    splits (bf16 OR fp16) fail: fp16 cvt_pkrtz is RTZ (biased) so dropped
//    residuals accumulate LINEARLY over K=64 -> ~2^-16 -> gate flips -> absmax 4+.
//  - Jacobian has no sign decisions -> fp16 2-level 3-product is safe (2^-16
//    relative on dJ -> ~1e-4 on log|dJ|).
__device__ __forceinline__ unsigned rne2(float x0, float x1, float &h0, float &h1) {
    unsigned u0 = __float_as_uint(x0), u1 = __float_as_uint(x1);
    unsigned r0 = u0 + 0x7FFFu + ((u0 >> 16) & 1u);
    unsigned r1 = u1 + 0x7FFFu + ((u1 >> 16) & 1u);
    h0 = __uint_as_float(r0 & 0xFFFF0000u);
    h1 = __uint_as_float(r1 & 0xFFFF0000u);
    return __builtin_amdgcn_perm(r1, r0, 0x07060302u);  // [r0.hi16 | r1.hi16<<16]
}

// truncation pair-round (cheap — 3 ops): h = x with low 16 bits cleared (exact x-h)
__device__ __forceinline__ unsigned trunc2(float x0, float x1, float &h0, float &h1) {
    unsigned u0 = __float_as_uint(x0), u1 = __float_as_uint(x1);
    h0 = __uint_as_float(u0 & 0xFFFF0000u);
    h1 = __uint_as_float(u1 & 0xFFFF0000u);
    return __builtin_amdgcn_perm(u1, u0, 0x07060302u);
}

// full-RNE 3-way split (prep: weights)
__device__ __forceinline__ void split3_2(float x0, float x1,
                                         unsigned &p1, unsigned &p2, unsigned &p3) {
    float h0, h1; p1 = rne2(x0, x1, h0, h1);
    float e0 = x0 - h0, e1 = x1 - h1;      // exact
    float m0, m1; p2 = rne2(e0, e1, m0, m1);
    float f0 = e0 - m0, f1 = e1 - m1;      // exact
    float t0, t1; p3 = rne2(f0, f1, t0, t1);
}

// trunc-trunc-RNE 3-way split (main-kernel act/emb splits). Levels 1-2 truncate
// but leave an EXACT fp32 residual; only the last level rounds (RNE, unbiased,
// ~2^-25). 15 vs 23 VALU ops/pair. Validated: absmax 1.0.
__device__ __forceinline__ void split3t_2(float x0, float x1,
                                          unsigned &p1, unsigned &p2, unsigned &p3) {
    float h0, h1; p1 = trunc2(x0, x1, h0, h1);
    float e0 = x0 - h0, e1 = x1 - h1;      // exact
    float m0, m1; p2 = trunc2(e0, e1, m0, m1);
    float f0 = e0 - m0, f1 = e1 - m1;      // exact
    float t0, t1; p3 = rne2(f0, f1, t0, t1);   // h outputs DCE'd
}

union FragU { unsigned u[4]; bf16x8 v; };

__device__ __forceinline__ void splitA3t(const float4 a0, const float4 a1,
                                         bf16x8 &A1, bf16x8 &A2, bf16x8 &A3) {
    FragU U1, U2, U3;
    split3t_2(a0.x, a0.y, U1.u[0], U2.u[0], U3.u[0]);
    split3t_2(a0.z, a0.w, U1.u[1], U2.u[1], U3.u[1]);
    split3t_2(a1.x, a1.y, U1.u[2], U2.u[2], U3.u[2]);
    split3t_2(a1.z, a1.w, U1.u[3], U2.u[3], U3.u[3]);
    A1 = U1.v; A2 = U2.v; A3 = U3.v;
}

// ---------------- fp16 splits (Jacobian path: values only) ----------------
__device__ __forceinline__ void split2h(float x0, float x1, unsigned &p1, unsigned &p2) {
    fp16x2 h = __builtin_amdgcn_cvt_pkrtz(x0, x1);
    __builtin_memcpy(&p1, &h, 4);
    fp16x2 l = __builtin_amdgcn_cvt_pkrtz(x0 - (float)h[0], x1 - (float)h[1]);
    __builtin_memcpy(&p2, &l, 4);
}

union FragH { unsigned u[4]; f16x8 v; };

__device__ __forceinline__ void splitA2h(const float4 a0, const float4 a1,
                                         f16x8 &A1, f16x8 &A2) {
    FragH U1, U2;
    split2h(a0.x, a0.y, U1.u[0], U2.u[0]);
    split2h(a0.z, a0.w, U1.u[1], U2.u[1]);
    split2h(a1.x, a1.y, U1.u[2], U2.u[2]);
    split2h(a1.z, a1.w, U1.u[3], U2.u[3]);
    A1 = U1.v; A2 = U2.v;
}

// ---- prep: weights -> B-fragments in d_ws; also zeroes out_ld ----
// B-frag (16x16x32): lane holds B[k=(lane>>4)*8+j][n=lane&15] = W[n][k], j=0..7.
__global__ void prep_weights(const float* __restrict__ W0, const float* __restrict__ W1,
                             const float* __restrict__ W2, unsigned* __restrict__ ws,
                             float* __restrict__ out_ld) {
    int id = blockIdx.x * blockDim.x + threadIdx.x;   // 16*9216 total
    if (id < kN) out_ld[id] = 0.f;                    // replaces hipMemsetAsync
    if (id >= 16 * 9216) return;
    int d = id / 9216, rem = id - d * 9216;
    unsigned* wd = ws + (size_t)d * kWsDwPerD;

    if (rem < 5120) {                                  // forward bf16 3-level
        float x0, x1; unsigned o1, o2, o3;
        if (rem < 1024) {                              // W0 (K=32, 1 ktile)
            int idx = rem, j2 = idx & 3, ln = (idx >> 2) & 63, nt = (idx >> 8) & 3;
            int n_ = nt * 16 + (ln & 15), k_ = ((ln >> 4) << 3) + 2 * j2;
            const float* g = W0 + (size_t)d * kH * 33;
            x0 = g[n_ * 33 + k_]; x1 = g[n_ * 33 + k_ + 1];
            o1 = idx; o2 = 1024 + idx; o3 = 2048 + idx;
        } else if (rem < 3072) {                       // W1 (K=64, 2 ktiles)
            int idx = rem - 1024, j2 = idx & 3, ln = (idx >> 2) & 63;
            int kt = (idx >> 8) & 1, nt = (idx >> 9) & 3;
            int n_ = nt * 16 + (ln & 15), k_ = kt * 32 + ((ln >> 4) << 3) + 2 * j2;
            const float* g = W1 + (size_t)d * kH * kH;
            x0 = g[n_ * 64 + k_]; x1 = g[n_ * 64 + k_ + 1];
            o1 = 3072 + idx; o2 = 5120 + idx; o3 = 7168 + idx;
        } else {                                       // W2
            int idx = rem - 3072, j2 = idx & 3, ln = (idx >> 2) & 63;
            int kt = (idx >> 8) & 1, nt = (idx >> 9) & 3;
            int n_ = nt * 16 + (ln & 15), k_ = kt * 32 + ((ln >> 4) << 3) + 2 * j2;
            const float* g = W2 + (size_t)d * kH * kH;
            x0 = g[n_ * 64 + k_]; x1 = g[n_ * 64 + k_ + 1];
            o1 = 9216 + idx; o2 = 11264 + idx; o3 = 13312 + idx;
        }
        unsigned p1, p2, p3; split3_2(x0, x1, p1, p2, p3);
        wd[o1] = p1; wd[o2] = p2; wd[o3] = p3;
    } else {                                           // jacobian fp16 2-level
        int idx, base; const float* g;
        if (rem < 7168) { idx = rem - 5120; base = 15360; g = W1 + (size_t)d * kH * kH; }
        else            { idx = rem - 7168; base = 19456; g = W2 + (size_t)d * kH * kH; }
        int j2 = idx & 3, ln = (idx >> 2) & 63;
        int kt = (idx >> 8) & 1, nt = (idx >> 9) & 3;
        int n_ = nt * 16 + (ln & 15), k_ = kt * 32 + ((ln >> 4) << 3) + 2 * j2;
        float x0 = g[n_ * 64 + k_], x1 = g[n_ * 64 + k_ + 1];
        unsigned p1, p2; split2h(x0, x1, p1, p2);
        wd[base + idx] = p1; wd[base + 2048 + idx] = p2;
    }
}

#define MFMA(A, B, C)  __builtin_amdgcn_mfma_f32_16x16x32_bf16((A), (B), (C), 0, 0, 0)
#define MFMAH(A, B, C) __builtin_amdgcn_mfma_f32_16x16x32_f16((A), (B), (C), 0, 0, 0)

// forward K=64 layer, 2 m-tiles: 6-product bf16x3, level-ordered (one B level live)
__device__ __forceinline__ void layer64_f(f32x4 acc[2][4],
                                          const float* r0, const float* r1,
                                          const unsigned* w1, const unsigned* w2,
                                          const unsigned* w3, int lane, int q) {
    #pragma unroll
    for (int kt = 0; kt < 2; ++kt) {
        bf16x8 A1[2], A2[2], A3[2];
        {
            const float4 a0 = *(const float4*)(r0 + kt * 32 + q * 8);
            const float4 a1 = *(const float4*)(r0 + kt * 32 + q * 8 + 4);
            splitA3t(a0, a1, A1[0], A2[0], A3[0]);
            const float4 b0_ = *(const float4*)(r1 + kt * 32 + q * 8);
            const float4 b1_ = *(const float4*)(r1 + kt * 32 + q * 8 + 4);
            splitA3t(b0_, b1_, A1[1], A2[1], A3[1]);
        }
        bf16x8 B[4];
        #pragma unroll
        for (int nt = 0; nt < 4; ++nt) B[nt] = *(const bf16x8*)(w1 + (((nt * 2 + kt) * 64 + lane) << 2));
        #pragma unroll
        for (int nt = 0; nt < 4; ++nt)
            #pragma unroll
            for (int mt = 0; mt < 2; ++mt) {
                acc[mt][nt] = MFMA(A3[mt], B[nt], acc[mt][nt]);
                acc[mt][nt] = MFMA(A2[mt], B[nt], acc[mt][nt]);
                acc[mt][nt] = MFMA(A1[mt], B[nt], acc[mt][nt]);
            }
        #pragma unroll
        for (int nt = 0; nt < 4; ++nt) B[nt] = *(const bf16x8*)(w2 + (((nt * 2 + kt) * 64 + lane) << 2));
        #pragma unroll
        for (int nt = 0; nt < 4; ++nt)
            #pragma unroll
            for (int mt = 0; mt < 2; ++mt) {
                acc[mt][nt] = MFMA(A2[mt], B[nt], acc[mt][nt]);
                acc[mt][nt] = MFMA(A1[mt], B[nt], acc[mt][nt]);
            }
        #pragma unroll
        for (int nt = 0; nt < 4; ++nt) B[nt] = *(const bf16x8*)(w3 + (((nt * 2 + kt) * 64 + lane) << 2));
        #pragma unroll
        for (int nt = 0; nt < 4; ++nt)
            #pragma unroll
            for (int mt = 0; mt < 2; ++mt)
                acc[mt][nt] = MFMA(A1[mt], B[nt], acc[mt][nt]);
    }
}

// Jacobian K=64 layer, 2 m-tiles: fp16 2-way split, 3 products (values only)
__device__ __forceinline__ void layer64_jh(f32x4 acc[2][4],
                                           const float* r0, const float* r1,
                                           const unsigned* wl1, const unsigned* wl2,
                                           int lane, int q) {
    #pragma unroll
    for (int kt = 0; kt < 2; ++kt) {
        f16x8 A1[2], A2[2];
        {
            const float4 a0 = *(const float4*)(r0 + kt * 32 + q * 8);
            const float4 a1 = *(const float4*)(r0 + kt * 32 + q * 8 + 4);
            splitA2h(a0, a1, A1[0], A2[0]);
            const float4 b0_ = *(const float4*)(r1 + kt * 32 + q * 8);
            const float4 b1_ = *(const float4*)(r1 + kt * 32 + q * 8 + 4);
            splitA2h(b0_, b1_, A1[1], A2[1]);
        }
        f16x8 B[4];
        #pragma unroll
        for (int nt = 0; nt < 4; ++nt) B[nt] = *(const f16x8*)(wl1 + (((nt * 2 + kt) * 64 + lane) << 2));
        #pragma unroll
        for (int nt = 0; nt < 4; ++nt)
            #pragma unroll
            for (int mt = 0; mt < 2; ++mt) {
                acc[mt][nt] = MFMAH(A2[mt], B[nt], acc[mt][nt]);
                acc[mt][nt] = MFMAH(A1[mt], B[nt], acc[mt][nt]);
            }
        #pragma unroll
        for (int nt = 0; nt < 4; ++nt) B[nt] = *(const f16x8*)(wl2 + (((nt * 2 + kt) * 64 + lane) << 2));
        #pragma unroll
        for (int nt = 0; nt < 4; ++nt)
            #pragma unroll
            for (int mt = 0; mt < 2; ++mt)
                acc[mt][nt] = MFMAH(A1[mt], B[nt], acc[mt][nt]);
    }
}

// Main: block = 128 threads = 2 waves; each wave owns 32 tasks (2 m-tiles of 16),
// all waves same d. C/D: task-row = mt*16 + (lane>>4)*4 + reg, unit = nt*16 + (lane&15).
// act rows carry layer boundaries; waves touch disjoint rows -> no barriers.
// History: r12: do NOT pre-split emb to global (exposed latency). r14: do NOT
// use fp16 2-way for the forward (RTZ bias -> linear error growth -> gate flips).
__global__ __launch_bounds__(128, 2) void np_mfma_kernel(
    const float* __restrict__ x, const float* __restrict__ emb,
    const float* __restrict__ W0, const float* __restrict__ b0,
    const float* __restrict__ b1, const float* __restrict__ b2,
    const float* __restrict__ Wo, const float* __restrict__ bo,
    const unsigned* __restrict__ ws,
    float* __restrict__ out_res, float* __restrict__ out_ld)
{
    __shared__ __align__(16) float act[64 * AS];    // 17408 B

    const int tid  = threadIdx.x;
    const int lane = tid & 63;
    const int wave = __builtin_amdgcn_readfirstlane(tid >> 6);
    const int c = lane & 15, q = lane >> 4;
    const int tb = wave * 32;                        // block-local task base
    const int d  = blockIdx.y;
    const int nW = blockIdx.x * 64 + tb;             // global task base of wave

    // x for task nW + (q>>1)*16 + c  (64 lanes cover 32 tasks, 2-way redundant)
    const int nX  = nW + ((q >> 1) << 4) + c;
    const int bbX = nX / kLen;
    const float xm = x[((size_t)(bbX * kT + (nX - bbX * kLen) + 2)) * kD + d];
    float xr[2][4];
    #pragma unroll
    for (int mt = 0; mt < 2; ++mt)
        #pragma unroll
        for (int r = 0; r < 4; ++r)
            xr[mt][r] = __shfl(xm, mt * 32 + q * 4 + r, 64);  // src lane = 32*mt + row

    const float* W0g = W0 + (size_t)d * kH * 33;
    float b0v[4], wov[4], w0xv[4];
    #pragma unroll
    for (int nt = 0; nt < 4; ++nt) {
        const int u = nt * 16 + c;
        b0v[nt]  = b0[d * kH + u];
        wov[nt]  = Wo[d * kH + u];
        w0xv[nt] = W0g[u * 33 + 32];                 // last input column of W0
    }
    const float bov = bo[d];
    const unsigned* wd = ws + (size_t)d * kWsDwPerD;
    const float* r0 = &act[(tb + c) * AS];           // A rows for m-tile 0 / 1
    const float* r1 = &act[(tb + 16 + c) * AS];

    unsigned m0 = 0, m1 = 0, m2 = 0;                 // gate masks: bit = mt*16+nt*4+r
    f32x4 acc[2][4];

    // ---------- L0 (K=32): z0 = W0[:,:32]@emb + x*W0[:,32] + b0 ----------
    {
        bf16x8 A1[2], A2[2], A3[2];
        #pragma unroll
        for (int mt = 0; mt < 2; ++mt) {
            const int nA = nW + mt * 16 + c;
            const int bb = nA / kLen;
            const size_t src = (size_t)(bb * kT + (nA - bb * kLen) + 2);
            const float4* ep = (const float4*)(emb + src * kE + q * 8);
            splitA3t(ep[0], ep[1], A1[mt], A2[mt], A3[mt]);
        }
        #pragma unroll
        for (int mt = 0; mt < 2; ++mt)
            #pragma unroll
            for (int nt = 0; nt < 4; ++nt) {
                f32x4 a;
                #pragma unroll
                for (int r = 0; r < 4; ++r) a[r] = fmaf(xr[mt][r], w0xv[nt], b0v[nt]);
                acc[mt][nt] = a;
            }
        bf16x8 B[4];
        #pragma unroll
        for (int nt = 0; nt < 4; ++nt) B[nt] = *(const bf16x8*)(wd + ((nt * 64 + lane) << 2));
        #pragma unroll
        for (int nt = 0; nt < 4; ++nt)
            #pragma unroll
            for (int mt = 0; mt < 2; ++mt) {
                acc[mt][nt] = MFMA(A3[mt], B[nt], acc[mt][nt]);
                acc[mt][nt] = MFMA(A2[mt], B[nt], acc[mt][nt]);
                acc[mt][nt] = MFMA(A1[mt], B[nt], acc[mt][nt]);
            }
        #pragma unroll
        for (int nt = 0; nt < 4; ++nt) B[nt] = *(const bf16x8*)(wd + 1024 + ((nt * 64 + lane) << 2));
        #pragma unroll
        for (int nt = 0; nt < 4; ++nt)
            #pragma unroll
            for (int mt = 0; mt < 2; ++mt) {
                acc[mt][nt] = MFMA(A2[mt], B[nt], acc[mt][nt]);
                acc[mt][nt] = MFMA(A1[mt], B[nt], acc[mt][nt]);
            }
        #pragma unroll
        for (int nt = 0; nt < 4; ++nt) B[nt] = *(const bf16x8*)(wd + 2048 + ((nt * 64 + lane) << 2));
        #pragma unroll
        for (int nt = 0; nt < 4; ++nt)
            #pragma unroll
            for (int mt = 0; mt < 2; ++mt)
                acc[mt][nt] = MFMA(A1[mt], B[nt], acc[mt][nt]);
        #pragma unroll
        for (int mt = 0; mt < 2; ++mt)
            #pragma unroll
            for (int nt = 0; nt < 4; ++nt)
                #pragma unroll
                for (int r = 0; r < 4; ++r) {
                    float z = acc[mt][nt][r];
                    m0 |= (unsigned)(z >= 0.f) << (mt * 16 + nt * 4 + r);
                    act[(tb + mt * 16 + q * 4 + r) * AS + nt * 16 + c] = fmaxf(z, z * kSlope);
                }
    }

    // ---------- L1 ----------
    {
        #pragma unroll
        for (int nt = 0; nt < 4; ++nt) {
            const float bv = b1[d * kH + nt * 16 + c];
            #pragma unroll
            for (int mt = 0; mt < 2; ++mt) {
                f32x4 a;
                #pragma unroll
                for (int r = 0; r < 4; ++r) a[r] = bv;
                acc[mt][nt] = a;
            }
        }
        layer64_f(acc, r0, r1, wd + 3072, wd + 5120, wd + 7168, lane, q);
        #pragma unroll
        for (int mt = 0; mt < 2; ++mt)
            #pragma unroll
            for (int nt = 0; nt < 4; ++nt)
                #pragma unroll
                for (int r = 0; r < 4; ++r) {
                    float z = acc[mt][nt][r];
                    m1 |= (unsigned)(z >= 0.f) << (mt * 16 + nt * 4 + r);
                    act[(tb + mt * 16 + q * 4 + r) * AS + nt * 16 + c] = fmaxf(z, z * kSlope);
                }
    }

    // ---------- L2 + fused forward head ----------
    {
        #pragma unroll
        for (int nt = 0; nt < 4; ++nt) {
            const float bv = b2[d * kH + nt * 16 + c];
            #pragma unroll
            for (int mt = 0; mt < 2; ++mt) {
                f32x4 a;
                #pragma unroll
                for (int r = 0; r < 4; ++r) a[r] = bv;
                acc[mt][nt] = a;
            }
        }
        layer64_f(acc, r0, r1, wd + 9216, wd + 11264, wd + 13312, lane, q);
        float pr[2][4] = {{0.f,0.f,0.f,0.f},{0.f,0.f,0.f,0.f}};
        #pragma unroll
        for (int mt = 0; mt < 2; ++mt)
            #pragma unroll
            for (int nt = 0; nt < 4; ++nt)
                #pragma unroll
                for (int r = 0; r < 4; ++r) {
                    float z = acc[mt][nt][r];
                    m2 |= (unsigned)(z >= 0.f) << (mt * 16 + nt * 4 + r);
                    pr[mt][r] = fmaf(wov[nt], fmaxf(z, z * kSlope), pr[mt][r]);
                }
        #pragma unroll
        for (int mt = 0; mt < 2; ++mt)
            #pragma unroll
            for (int r = 0; r < 4; ++r) {
                #pragma unroll
                for (int s = 1; s < 16; s <<= 1) pr[mt][r] += __shfl_xor(pr[mt][r], s, 16);
            }
        if (c == 0) {
            #pragma unroll
            for (int mt = 0; mt < 2; ++mt)
                #pragma unroll
                for (int r = 0; r < 4; ++r)
                    out_res[(size_t)(nW + mt * 16 + q * 4 + r) * kD + d] = pr[mt][r] + bov;
        }
    }

    // ---------- Jacobian t0 = g0 * W0[:, 32] ----------
    #pragma unroll
    for (int mt = 0; mt < 2; ++mt)
        #pragma unroll
        for (int nt = 0; nt < 4; ++nt)
            #pragma unroll
            for (int r = 0; r < 4; ++r)
                act[(tb + mt * 16 + q * 4 + r) * AS + nt * 16 + c] =
                    (((m0 >> (mt * 16 + nt * 4 + r)) & 1u) ? 1.f : kSlope) * w0xv[nt];

    // ---------- jac L1: t1 = g1 * (W1 @ t0)  [fp16 2-way, 3 products] ----------
    {
        #pragma unroll
        for (int mt = 0; mt < 2; ++mt)
            #pragma unroll
            for (int nt = 0; nt < 4; ++nt) acc[mt][nt] = (f32x4){0.f, 0.f, 0.f, 0.f};
        layer64_jh(acc, r0, r1, wd + 15360, wd + 17408, lane, q);
        #pragma unroll
        for (int mt = 0; mt < 2; ++mt)
            #pragma unroll
            for (int nt = 0; nt < 4; ++nt)
                #pragma unroll
                for (int r = 0; r < 4; ++r)
                    act[(tb + mt * 16 + q * 4 + r) * AS + nt * 16 + c] =
                        (((m1 >> (mt * 16 + nt * 4 + r)) & 1u) ? 1.f : kSlope) * acc[mt][nt][r];
    }

    // ---------- jac L2 + fused Jacobian head ----------
    {
        #pragma unroll
        for (int mt = 0; mt < 2; ++mt)
            #pragma unroll
            for (int nt = 0; nt < 4; ++nt) acc[mt][nt] = (f32x4){0.f, 0.f, 0.f, 0.f};
        layer64_jh(acc, r0, r1, wd + 19456, wd + 21504, lane, q);
        float pr[2][4] = {{0.f,0.f,0.f,0.f},{0.f,0.f,0.f,0.f}};
        #pragma unroll
        for (int mt = 0; mt < 2; ++mt)
            #pragma unroll
            for (int nt = 0; nt < 4; ++nt)
                #pragma unroll
                for (int r = 0; r < 4; ++r) {
                    float t = (((m2 >> (mt * 16 + nt * 4 + r)) & 1u) ? 1.f : kSlope) * acc[mt][nt][r];
                    pr[mt][r] = fmaf(wov[nt], t, pr[mt][r]);
                }
        #pragma unroll
        for (int mt = 0; mt < 2; ++mt)
            #pragma unroll
            for (int r = 0; r < 4; ++r) {
                #pragma unroll
                for (int s = 1; s < 16; s <<= 1) pr[mt][r] += __shfl_xor(pr[mt][r], s, 16);
            }
        if (c == 0) {
            #pragma unroll
            for (int mt = 0; mt < 2; ++mt)
                #pragma unroll
                for (int r = 0; r < 4; ++r)
                    atomicAdd(&out_ld[nW + mt * 16 + q * 4 + r], __logf(fabsf(pr[mt][r])));
        }
    }
}

extern "C" void kernel_launch(void* const* d_in, const int* in_sizes, int n_in,
                              void* d_out, int out_size, void* d_ws, size_t ws_size,
                              hipStream_t stream) {
    const float* x  = (const float*)d_in[0];
    const float* em = (const float*)d_in[1];
    const float* W0 = (const float*)d_in[2];
    const float* b0 = (const float*)d_in[3];
    const float* W1 = (const float*)d_in[4];
    const float* b1 = (const float*)d_in[5];
    const float* W2 = (const float*)d_in[6];
    const float* b2 = (const float*)d_in[7];
    const float* Wo = (const float*)d_in[8];
    const float* bo = (const float*)d_in[9];

    float* out_res = (float*)d_out;                    // [N, D] residuals
    float* out_ld  = (float*)d_out + (size_t)kN * kD;  // [N] log|det J|
    unsigned* ws   = (unsigned*)d_ws;                  // 1,507,328 B of weight frags

    prep_weights<<<dim3(16 * 9216 / 256), dim3(256), 0, stream>>>(W0, W1, W2, ws, out_ld);
    np_mfma_kernel<<<dim3(kN / 64, kD), dim3(128), 0, stream>>>(
        x, em, W0, b0, b1, b2, Wo, bo, ws, out_res, out_ld);
}